// Round 5
// baseline (229.900 us; speedup 1.0000x reference)
//
#include <hip/hip_runtime.h>
#include <hip/hip_bf16.h>
#include <stdint.h>

// Fastfood 2D conv, MI355X. fp32 I/O:
// input (16,256,32,32), B/G/S (1,4096), bias (512), P (4096) i32 -> out (16,512,32,32).
// Per pixel: patch j=kk*256+ch (2304, pad 4096), *B, FWHT4096, perm P, *G, FWHT4096,
// *S[0:512]+bias.
//
// R5: pre-pass transposes input NCHW f32 -> NHWC bf16 in d_ws (coalesced both ways)
// so the main kernel's patch loads (channel = lane) are coalesced u16 reads.
// Main kernel: block=(b,oh), pixel pairs (2q,2q+1) bf16x2, FWHT = 3x radix-16 with
// double-buffered swizzled LDS exchange (5 barriers/iter, addresses precomputed).
// Output accumulates in a 16 KB LDS region, flushed twice as 64 B half-rows
// (full cache lines). LDS = 48 KB -> 3 blocks/CU (12 waves) for barrier hiding.

__device__ __forceinline__ float bf2f(uint16_t u) {
    union { uint32_t i; float f; } c; c.i = ((uint32_t)u) << 16; return c.f;
}
__device__ __forceinline__ uint16_t f2bf(float f) {  // RNE
    uint32_t u = __float_as_uint(f);
    return (uint16_t)((u + 0x7FFFu + ((u >> 16) & 1u)) >> 16);
}
__device__ __forceinline__ int swz(int j) {
    return j ^ ((j >> 5) & 7) ^ (((j >> 8) & 1) * 24) ^ (((j >> 9) & 1) * 8);
}
__device__ __forceinline__ uint32_t pk2(float a, float b) {
    __hip_bfloat162 h = __float22bfloat162_rn(make_float2(a, b));
    union { __hip_bfloat162 h; uint32_t u; } c; c.h = h; return c.u;
}
__device__ __forceinline__ float2 unpk(uint32_t u) {
    return make_float2(__uint_as_float(u << 16), __uint_as_float(u & 0xFFFF0000u));
}
__device__ __forceinline__ void h16p(float2* x) {
    #pragma unroll
    for (int h = 1; h < 16; h <<= 1) {
        #pragma unroll
        for (int g = 0; g < 16; g += 2 * h) {
            #pragma unroll
            for (int u = g; u < g + h; ++u) {
                float2 a = x[u], b = x[u + h];
                x[u]     = make_float2(a.x + b.x, a.y + b.y);  // v_pk_add_f32
                x[u + h] = make_float2(a.x - b.x, a.y - b.y);
            }
        }
    }
}

#define STW(abyte, off, w) \
    (*reinterpret_cast<uint32_t*>(reinterpret_cast<char*>(lds) + (abyte) + (off)) = (w))
#define LDW(abyte, off) \
    (*reinterpret_cast<const uint32_t*>(reinterpret_cast<const char*>(lds) + (abyte) + (off)))

// One pixel pair (2q, 2q+1). PAR in {0,1}: exchange buffers alternate as immediates.
#define PROC(PAR)                                                                  \
{                                                                                  \
    const int q = 2 * m + (PAR);                                                   \
    constexpr int OA = (PAR) * 16384, OB = (1 - (PAR)) * 16384;                    \
    float2 x[16];                                                                  \
    _Pragma("unroll")                                                              \
    for (int kh = 0; kh < 3; ++kh) {                                               \
        float lm = 0.f, l0 = 0.f, l1 = 0.f, lp = 0.f;                              \
        if (okk[kh]) {                                                             \
            const uint16_t* p = rT[kh] + q * 512;   /* col 2q, channel t */        \
            l0 = bf2f(p[0]); l1 = bf2f(p[256]);                                    \
            if (q > 0)  lm = bf2f(p[-256]);                                        \
            if (q < 15) lp = bf2f(p[512]);                                         \
        }                                                                          \
        x[kh * 3 + 0] = make_float2(lm * Bv[kh * 3 + 0], l0 * Bv[kh * 3 + 0]);     \
        x[kh * 3 + 1] = make_float2(l0 * Bv[kh * 3 + 1], l1 * Bv[kh * 3 + 1]);     \
        x[kh * 3 + 2] = make_float2(l1 * Bv[kh * 3 + 2], lp * Bv[kh * 3 + 2]);     \
    }                                                                              \
    _Pragma("unroll")                                                              \
    for (int r = 9; r < 16; ++r) x[r] = make_float2(0.f, 0.f);                     \
    h16p(x);                                          /* pass0 round A */          \
    _Pragma("unroll")                                                              \
    for (int r = 0; r < 16; ++r) STW(aA[r], OA, pk2(x[r].x, x[r].y));              \
    __syncthreads();                                                               \
    _Pragma("unroll")                                                              \
    for (int r = 0; r < 16; ++r) x[r] = unpk(LDW(aB[r], OA));                      \
    h16p(x);                                          /* round B */                \
    _Pragma("unroll")                                                              \
    for (int r = 0; r < 16; ++r) STW(aB[r], OB, pk2(x[r].x, x[r].y));              \
    __syncthreads();                                                               \
    _Pragma("unroll")                                                              \
    for (int r = 0; r < 16; ++r) x[r] = unpk(LDW(aC[r], OB));                      \
    h16p(x);                                          /* round C */                \
    _Pragma("unroll")                                                              \
    for (int r = 0; r < 16; ++r) STW(aC[r], OA, pk2(x[r].x, x[r].y));              \
    __syncthreads();                                                               \
    _Pragma("unroll")                                                              \
    for (int r = 0; r < 16; ++r) {                    /* perm + G -> A layout */   \
        float2 v = unpk(LDW(PA[r], OA));                                           \
        x[r] = make_float2(Gv[r] * v.x, Gv[r] * v.y);                              \
    }                                                                              \
    h16p(x);                                          /* pass1 round A */          \
    _Pragma("unroll")                                                              \
    for (int r = 0; r < 16; ++r) STW(aA[r], OB, pk2(x[r].x, x[r].y));              \
    __syncthreads();                                                               \
    _Pragma("unroll")                                                              \
    for (int r = 0; r < 16; ++r) x[r] = unpk(LDW(aB[r], OB));                      \
    h16p(x);                                          /* round B */                \
    _Pragma("unroll")                                                              \
    for (int r = 0; r < 16; ++r) STW(aB[r], OA, pk2(x[r].x, x[r].y));              \
    __syncthreads();                                                               \
    _Pragma("unroll")                                                              \
    for (int r = 0; r < 16; ++r) x[r] = unpk(LDW(aC[r], OA));                      \
    h16p(x);                                          /* round C: j = 16t + r */   \
    if (t < 32) {                                     /* S*x+bias -> accum q&7 */  \
        const int qb = 8192 + 512 * (q & 7);                                       \
        _Pragma("unroll")                                                          \
        for (int r = 0; r < 16; ++r)                                               \
            lds[qb + epiW[r]] =                                                    \
                pk2(Sv[r] * x[r].x + Cv[r], Sv[r] * x[r].y + Cv[r]);               \
    }                                                                              \
}

__global__ __launch_bounds__(256, 3)
void fastfood_kernel(const uint16_t* __restrict__ inT,   // (b,h,w,c) bf16
                     const float* __restrict__ Bm,
                     const float* __restrict__ Gm,
                     const float* __restrict__ Sm,
                     const float* __restrict__ bias,
                     const int* __restrict__ P,
                     float* __restrict__ out)
{
    // [0,4096): exchange buf0 | [4096,8192): buf1 | [8192,12288): accum (8 pairs)
    __shared__ uint32_t lds[12288];   // 48 KiB -> 3 blocks/CU

    const int t  = threadIdx.x;
    const int t1 = t >> 4, t0 = t & 15;
    const int b  = blockIdx.x >> 5;
    const int oh = blockIdx.x & 31;

    // ---- precomputed LDS byte addresses (loop-invariant, live in VGPRs)
    int aA[16], aB[16], aC[16], PA[16];
    float Gv[16];
    #pragma unroll
    for (int r = 0; r < 16; ++r) {
        aA[r] = swz(256 * r + t) * 4;
        aB[r] = swz(256 * t1 + 16 * r + t0) * 4;
        aC[r] = swz(256 * t1 + 16 * t0 + r) * 4;
        PA[r] = swz(P[r * 256 + t]) * 4;
        Gv[r] = Gm[r * 256 + t];
    }
    float Bv[9];
    #pragma unroll
    for (int r = 0; r < 9; ++r) Bv[r] = Bm[r * 256 + t];
    float Sv[16], Cv[16];
    if (t < 32) {
        #pragma unroll
        for (int r = 0; r < 16; ++r) { Sv[r] = Sm[16 * t + r]; Cv[r] = bias[16 * t + r]; }
    }
    int epiW[16];
    #pragma unroll
    for (int r = 0; r < 16; ++r) epiW[r] = 16 * t + (r ^ ((t >> 1) & 7));

    // ---- patch row pointers in NHWC bf16, channel = t (coalesced u16 loads)
    const uint16_t* rT[3]; bool okk[3];
    #pragma unroll
    for (int kh = 0; kh < 3; ++kh) {
        const int ih = oh - 1 + kh;
        okk[kh] = (unsigned)ih < 32u;
        rT[kh]  = inT + ((size_t)(b * 32 + ih) * 32) * 256 + t;
    }

    #pragma unroll 1
    for (int m = 0; m < 8; ++m) {
        PROC(0)
        PROC(1)
        if (m == 3 || m == 7) {
            // flush half the output: pixels ow = (m>>2)*16 .. +15 (64 B = full lines)
            __syncthreads();
            const int hw  = m >> 2;
            const int oc0 = 2 * t, oc1 = 2 * t + 1;
            const int c0 = (oc0 & ~15) | ((oc0 & 15) ^ ((oc0 >> 5) & 7));
            const int c1 = (oc1 & ~15) | ((oc1 & 15) ^ ((oc1 >> 5) & 7));
            float r0[16], r1[16];
            #pragma unroll
            for (int qq = 0; qq < 8; ++qq) {
                float2 va = unpk(lds[8192 + 512 * qq + c0]);
                float2 vb = unpk(lds[8192 + 512 * qq + c1]);
                r0[2 * qq] = va.x; r0[2 * qq + 1] = va.y;
                r1[2 * qq] = vb.x; r1[2 * qq + 1] = vb.y;
            }
            float* o0 = out + ((size_t)(b * 512 + oc0) * 1024 + oh * 32 + hw * 16);
            float* o1 = o0 + 1024;
            #pragma unroll
            for (int g = 0; g < 4; ++g) {
                *reinterpret_cast<float4*>(o0 + 4 * g) =
                    make_float4(r0[4 * g], r0[4 * g + 1], r0[4 * g + 2], r0[4 * g + 3]);
                *reinterpret_cast<float4*>(o1 + 4 * g) =
                    make_float4(r1[4 * g], r1[4 * g + 1], r1[4 * g + 2], r1[4 * g + 3]);
            }
            // no post-barrier needed: next PROC's accum writes sit behind 5 barriers
        }
    }
}

// NCHW f32 -> NHWC bf16, LDS-bounced, coalesced both directions.
__global__ __launch_bounds__(256)
void transpose_in(const float* __restrict__ in, uint16_t* __restrict__ inT)
{
    __shared__ uint16_t ldt[256 * 33];   // +1 halfword pad per channel row
    const int t = threadIdx.x;
    const int b = blockIdx.x >> 5, h = blockIdx.x & 31;

    #pragma unroll
    for (int i = 0; i < 8; ++i) {
        const int idx = t + i * 256;         // 2048 16-byte chunks
        const int part = idx & 7, c = idx >> 3;
        float4 v = *reinterpret_cast<const float4*>(
            in + ((size_t)(b * 256 + c) * 1024 + h * 32 + part * 4));
        const int a = c * 33 + part * 4;
        ldt[a]     = f2bf(v.x); ldt[a + 1] = f2bf(v.y);
        ldt[a + 2] = f2bf(v.z); ldt[a + 3] = f2bf(v.w);
    }
    __syncthreads();

    const int c0 = 2 * (t & 127);
    const int wbase = (t >> 7) * 16;
    uint32_t* outw = reinterpret_cast<uint32_t*>(inT + (size_t)(b * 32 + h) * 32 * 256);
    #pragma unroll
    for (int i = 0; i < 16; ++i) {
        const int w = wbase + i;
        const uint32_t lo = ldt[c0 * 33 + w];
        const uint32_t hi = ldt[(c0 + 1) * 33 + w];
        outw[(w * 256 + c0) >> 1] = lo | (hi << 16);
    }
}

extern "C" void kernel_launch(void* const* d_in, const int* in_sizes, int n_in,
                              void* d_out, int out_size, void* d_ws, size_t ws_size,
                              hipStream_t stream) {
    const float* in   = (const float*)d_in[0];
    const float* Bm   = (const float*)d_in[1];
    const float* Gm   = (const float*)d_in[2];
    const float* Sm   = (const float*)d_in[3];
    const float* bias = (const float*)d_in[4];
    const int*   P    = (const int*)d_in[5];
    float*    out = (float*)d_out;
    uint16_t* inT = (uint16_t*)d_ws;      // 16 MB NHWC bf16 staging

    dim3 grid(16 * 32), block(256);
    transpose_in<<<grid, block, 0, stream>>>(in, inT);
    fastfood_kernel<<<grid, block, 0, stream>>>(inT, Bm, Gm, Sm, bias, P, out);
}